// Round 4
// baseline (120.332 us; speedup 1.0000x reference)
//
#include <hip/hip_runtime.h>
#include <math.h>

// WayfinderAttention: B=1, H=16, T=2048, DH=64, D=64 neighbors. f32 in/out.
// R14: R13 (swizzle kept: FETCH 69.6->20.4MB, but dur unchanged => latency-
//      bound, not BW-bound; VALUBusy 35%, issue-floor ~12us, occupancy ~3.2
//      waves/SIMD) + SINGLE STRUCTURAL DELTA: 2 queries per wave (ILP).
//      Each wave runs two independent chains (adjacent t, same head; pairs
//      never cross heads since T=2048 even). Queries in flight per SIMD
//      ~3.2 -> ~6. K prefetch chunked 4 rows/query, V chunked 8 rows/query
//      to cap live VGPR ~140; __launch_bounds__(256,3) pins 3 waves/SIMD.
// Prediction: kernel 46 -> 28-34us, VALUBusy -> 50-60%, total -> ~97-103.

#define T_DIM 2048
#define DH    64
#define NB    64
#define WPB   4
#define QPW   2

__global__ __launch_bounds__(WPB * 64, 3)
void wayfinder_attn(const float* __restrict__ q,
                    const float* __restrict__ k,
                    const float* __restrict__ v,
                    const float* __restrict__ etb,
                    const int*   __restrict__ neigh_idx,
                    const int*   __restrict__ edge_type,
                    float*       __restrict__ out)
{
    __shared__ int   j_s[WPB][QPW][NB];
    __shared__ float b_s[WPB][QPW][NB];
    __shared__ float w_s[WPB][QPW][NB];
    __shared__ float dot_s[WPB][QPW][NB];

    const int lane = threadIdx.x & 63;
    const int wave = threadIdx.x >> 6;

    // XCD swizzle (kept from R13): 4096 blocks, 512/XCD -> 2 heads/XCD (L2-fit)
    const int bid = blockIdx.x;
    const int swz = (bid & 7) * 512 + (bid >> 3);

    const int wqb = (swz * WPB + wave) * QPW;     // even; pair stays in head

    int nv[QPW];
    // ---- per-query metadata + compaction ----
    #pragma unroll
    for (int qi = 0; qi < QPW; ++qi) {
        const int wq = wqb + qi;
        const int t  = wq & (T_DIM - 1);
        j_s[wave][qi][lane] = 0;
        b_s[wave][qi][lane] = 0.f;
        const int raw = neigh_idx[wq * NB + lane];
        const int et  = edge_type[wq * NB + lane];
        const bool valid = (raw >= 0) && (raw <= t);
        const int  sj    = min(max(raw, 0), T_DIM - 1);
        const float bias = (et != 0) ? etb[et - 1] : 0.f;
        const unsigned long long vb = __ballot(valid);
        nv[qi] = __popcll(vb);
        const int pos = __popcll(vb & ((1ull << lane) - 1ull));
        if (valid) { j_s[wave][qi][pos] = sj; b_s[wave][qi][pos] = bias; }
    }

    const int headbase = (wqb - (wqb & (T_DIM - 1))) * DH;   // floats
    const float* __restrict__ kh = k + headbase;
    const float* __restrict__ vh = v + headbase;

    // ---- score phase: per query, entry e = i*8+g8 gets 8 lanes (c8 dims);
    //      2 chunks of 4 iterations; both queries' loads in flight together ----
    const int c8 = lane & 7;
    const int g8 = lane >> 3;
    float4 qv0[QPW], qv1[QPW];
    #pragma unroll
    for (int qi = 0; qi < QPW; ++qi) {
        qv0[qi] = *(const float4*)(q + (wqb + qi) * DH + c8 * 8);
        qv1[qi] = *(const float4*)(q + (wqb + qi) * DH + c8 * 8 + 4);
    }

    #pragma unroll
    for (int c = 0; c < 2; ++c) {
        float4 kr0[QPW][4], kr1[QPW][4];
        #pragma unroll
        for (int qi = 0; qi < QPW; ++qi) {
            #pragma unroll
            for (int ii = 0; ii < 4; ++ii) {
                const int i = c * 4 + ii;
                if (i * 8 < nv[qi]) {
                    const int je = j_s[wave][qi][i * 8 + g8];
                    kr0[qi][ii] = *(const float4*)(kh + je * DH + c8 * 8);
                    kr1[qi][ii] = *(const float4*)(kh + je * DH + c8 * 8 + 4);
                }
            }
        }
        #pragma unroll
        for (int qi = 0; qi < QPW; ++qi) {
            #pragma unroll
            for (int ii = 0; ii < 4; ++ii) {
                const int i = c * 4 + ii;
                if (i * 8 < nv[qi]) {
                    float p = kr0[qi][ii].x * qv0[qi].x + kr0[qi][ii].y * qv0[qi].y
                            + kr0[qi][ii].z * qv0[qi].z + kr0[qi][ii].w * qv0[qi].w
                            + kr1[qi][ii].x * qv1[qi].x + kr1[qi][ii].y * qv1[qi].y
                            + kr1[qi][ii].z * qv1[qi].z + kr1[qi][ii].w * qv1[qi].w;
                    p += __shfl_xor(p, 1, 64);
                    p += __shfl_xor(p, 2, 64);
                    p += __shfl_xor(p, 4, 64);
                    if (c8 == 0) dot_s[wave][qi][i * 8 + g8] = p;
                }
            }
        }
    }

    // ---- softmax per query (two independent chains, interleaved by unroll) ----
    #pragma unroll
    for (int qi = 0; qi < QPW; ++qi) {
        const float mydot = dot_s[wave][qi][lane];
        const bool dval = lane < nv[qi];
        const float score = dval ? (mydot * 0.125f + b_s[wave][qi][lane]) : -INFINITY;
        float m = score;
        #pragma unroll
        for (int o = 32; o > 0; o >>= 1) m = fmaxf(m, __shfl_xor(m, o, 64));
        const float e = dval ? __expf(score - m) : 0.f;
        float s = e;
        #pragma unroll
        for (int o = 32; o > 0; o >>= 1) s += __shfl_xor(s, o, 64);
        w_s[wave][qi][lane] = e / fmaxf(s, 1e-20f);
    }

    // ---- PV: quarter qw x 4 entries per iteration; 2 rounds x 2 iters;
    //      16 lanes x float4 per V row; f32 accumulate ----
    const int qw   = lane >> 4;
    const int lp16 = lane & 15;
    float a0[QPW] = {0.f, 0.f}, a1[QPW] = {0.f, 0.f};
    float a2[QPW] = {0.f, 0.f}, a3[QPW] = {0.f, 0.f};
    #pragma unroll
    for (int r = 0; r < 2; ++r) {
        float4 vr[QPW][2][4];
        #pragma unroll
        for (int qi = 0; qi < QPW; ++qi) {
            #pragma unroll
            for (int i2 = 0; i2 < 2; ++i2) {
                const int i = r * 2 + i2;
                if (i * 16 < nv[qi]) {
                    const int4 jd = *(const int4*)&j_s[wave][qi][i * 16 + qw * 4];
                    vr[qi][i2][0] = *(const float4*)(vh + jd.x * DH + lp16 * 4);
                    vr[qi][i2][1] = *(const float4*)(vh + jd.y * DH + lp16 * 4);
                    vr[qi][i2][2] = *(const float4*)(vh + jd.z * DH + lp16 * 4);
                    vr[qi][i2][3] = *(const float4*)(vh + jd.w * DH + lp16 * 4);
                }
            }
        }
        #pragma unroll
        for (int qi = 0; qi < QPW; ++qi) {
            #pragma unroll
            for (int i2 = 0; i2 < 2; ++i2) {
                const int i = r * 2 + i2;
                if (i * 16 < nv[qi]) {
                    const float4 wd = *(const float4*)&w_s[wave][qi][i * 16 + qw * 4];
                    a0[qi] += wd.x * vr[qi][i2][0].x;  a1[qi] += wd.x * vr[qi][i2][0].y;
                    a2[qi] += wd.x * vr[qi][i2][0].z;  a3[qi] += wd.x * vr[qi][i2][0].w;
                    a0[qi] += wd.y * vr[qi][i2][1].x;  a1[qi] += wd.y * vr[qi][i2][1].y;
                    a2[qi] += wd.y * vr[qi][i2][1].z;  a3[qi] += wd.y * vr[qi][i2][1].w;
                    a0[qi] += wd.z * vr[qi][i2][2].x;  a1[qi] += wd.z * vr[qi][i2][2].y;
                    a2[qi] += wd.z * vr[qi][i2][2].z;  a3[qi] += wd.z * vr[qi][i2][2].w;
                    a0[qi] += wd.w * vr[qi][i2][3].x;  a1[qi] += wd.w * vr[qi][i2][3].y;
                    a2[qi] += wd.w * vr[qi][i2][3].z;  a3[qi] += wd.w * vr[qi][i2][3].w;
                }
            }
        }
    }
    // reduce across quarters; lanes 0..15 store one float4 per query
    #pragma unroll
    for (int qi = 0; qi < QPW; ++qi) {
        a0[qi] += __shfl_xor(a0[qi], 16, 64);  a1[qi] += __shfl_xor(a1[qi], 16, 64);
        a2[qi] += __shfl_xor(a2[qi], 16, 64);  a3[qi] += __shfl_xor(a3[qi], 16, 64);
        a0[qi] += __shfl_xor(a0[qi], 32, 64);  a1[qi] += __shfl_xor(a1[qi], 32, 64);
        a2[qi] += __shfl_xor(a2[qi], 32, 64);  a3[qi] += __shfl_xor(a3[qi], 32, 64);
    }
    if (lane < 16) {
        #pragma unroll
        for (int qi = 0; qi < QPW; ++qi) {
            float4 o; o.x = a0[qi]; o.y = a1[qi]; o.z = a2[qi]; o.w = a3[qi];
            *(float4*)(out + (wqb + qi) * DH + lane * 4) = o;
        }
    }
}

extern "C" void kernel_launch(void* const* d_in, const int* in_sizes, int n_in,
                              void* d_out, int out_size, void* d_ws, size_t ws_size,
                              hipStream_t stream)
{
    const float* q   = (const float*)d_in[0];
    const float* k   = (const float*)d_in[1];
    const float* v   = (const float*)d_in[2];
    const float* etb = (const float*)d_in[3];
    const int* neigh_idx = (const int*)d_in[4];
    const int* edge_type = (const int*)d_in[5];
    float* out = (float*)d_out;

    (void)d_ws; (void)ws_size;

    const int total_queries = 16 * T_DIM;                 // 32768
    const int blocks = total_queries / (WPB * QPW);       // 4096
    hipLaunchKernelGGL(wayfinder_attn, dim3(blocks), dim3(WPB * 64),
                       0, stream, q, k, v, etb, neigh_idx, edge_type, out);
}